// Round 16
// baseline (223.371 us; speedup 1.0000x reference)
//
#include <hip/hip_runtime.h>
#include <stdint.h>

#define SEQ 256
#define BATCH 32
#define IN_DIM 1024
#define HID 64
#define NPAD 1280
#define ROWS (SEQ*BATCH)   // 8192

// workspace layout (high-water 61,477,888 B — proven footprint):
//  [0,16.78M)   Xbf (prep->gemm) then Ypk bf16-packed (pack->chunks) [8192*928B = 7.6 MB]
//  [16.78M,..)  Wbf, bb, gate
//  [19.53M,61.48M) Y (gemm->pack) then DMh bf16-packed ΔM/Mstart (37.75 MB, nc=16)
#define XBF_OFF   0
#define YPK_OFF   0
#define WBF_OFF   16777216
#define BB_OFF    19398656
#define GATE_OFF  19403776
#define Y_OFF     19534848
#define DM_OFF    19534848

#define NC 16
#define CHL 16      // chunk length
#define NTILE 2     // CHL/8

// packed bf16 record, 232 dwords (928 B)/row:
// ushorts: k0[64]@0 | ka@64 | kb@128 | q@192 | v0@256 | va@320 | vb@384 | gate(4 fp32 raw)@448
// dwords:  k0@0..31 | ka@32 | kb@64 | q@96 | v0@128 | va@160 | vb@192 | gate@224
#define PKROW_D 232
#define TROW_D  232
#define TILEF_D (8*TROW_D)   // 1856 dwords/buffer; x2 = 14,848 B LDS

// DMh: per (c,b): [m(9)][i(64)][jpair(32)] uint32 (2 bf16) = 18432 u32 = 73.7 KB
#define DM_CB 18432

typedef __attribute__((ext_vector_type(8))) short short8;
typedef __attribute__((ext_vector_type(4))) float floatx4;

typedef const __attribute__((address_space(1))) unsigned int gas_u32;
typedef __attribute__((address_space(3))) unsigned int las_u32;
static __device__ __forceinline__ void gl_lds16(const void* g, void* l) {
  __builtin_amdgcn_global_load_lds((gas_u32*)g, (las_u32*)l, 16, 0, 0);
}

static __device__ __forceinline__ short f2bf(float f) {
  union { float f; uint32_t u; } a; a.f = f;
  uint32_t r = (a.u + 0x7FFFu + ((a.u >> 16) & 1u)) >> 16;  // RNE
  return (short)r;
}
static __device__ __forceinline__ float bflo(uint32_t u){ return __uint_as_float(u << 16); }
static __device__ __forceinline__ float bfhi(uint32_t u){ return __uint_as_float(u & 0xffff0000u); }
static __device__ __forceinline__ float bfu(unsigned short us){ return __uint_as_float(((uint32_t)us) << 16); }
static __device__ __forceinline__ uint32_t pk2bf(float a, float b) {
  return ((uint32_t)(unsigned short)f2bf(a)) | (((uint32_t)(unsigned short)f2bf(b)) << 16);
}

// ---------------- fused prep + gate (R16: one launch, blocks co-scheduled) ----------------
// blocks [0,2048): prep (fp32->bf16 X, concat/convert W, concat bias)
// blocks [2048,4096): fp32-exact gate logits + top-2
__global__ __launch_bounds__(256) void prep_gate_kernel(
    const float* __restrict__ X,
    const float* __restrict__ Wk, const float* __restrict__ bk,
    const float* __restrict__ Wv, const float* __restrict__ bv,
    const float* __restrict__ Wg, const float* __restrict__ bg,
    const float* __restrict__ Wq, const float* __restrict__ bq,
    short* __restrict__ Xbf, short* __restrict__ Wbf,
    float* __restrict__ bb, float4* __restrict__ gate)
{
  if (blockIdx.x < 2048) {
    int64_t idx = (int64_t)blockIdx.x * blockDim.x + threadIdx.x;
    int64_t stride = (int64_t)2048 * 256;
    const int64_t NX4 = (int64_t)ROWS * IN_DIM / 4;
    for (int64_t i = idx; i < NX4; i += stride) {
      float4 x = ((const float4*)X)[i];
      short4 s4;
      s4.x = f2bf(x.x); s4.y = f2bf(x.y); s4.z = f2bf(x.z); s4.w = f2bf(x.w);
      ((short4*)Xbf)[i] = s4;
    }
    const int64_t NW4 = (int64_t)NPAD * IN_DIM / 4;
    for (int64_t i = idx; i < NW4; i += stride) {
      int64_t e = i * 4;
      int r = (int)(e >> 10);
      int k = (int)(e & 1023);
      float4 x;
      if (r < 576)       x = *(const float4*)(Wk + (int64_t)r*1024 + k);
      else if (r < 1152) x = *(const float4*)(Wv + (int64_t)(r-576)*1024 + k);
      else if (r < 1216) x = *(const float4*)(Wq + (int64_t)(r-1152)*1024 + k);
      else               x = make_float4(0.f, 0.f, 0.f, 0.f);
      short4 s4;
      s4.x = f2bf(x.x); s4.y = f2bf(x.y); s4.z = f2bf(x.z); s4.w = f2bf(x.w);
      ((short4*)Wbf)[i] = s4;
    }
    for (int64_t i = idx; i < NPAD; i += stride) {
      int r = (int)i; float v;
      if (r < 576)       v = bk[r];
      else if (r < 1152) v = bv[r - 576];
      else if (r < 1216) v = bq[r - 1152];
      else               v = 0.f;
      bb[r] = v;
    }
  } else {
    const int lane = threadIdx.x & 63;
    const int row  = (blockIdx.x - 2048) * 4 + (threadIdx.x >> 6);
    const float* x = X + (int64_t)row * IN_DIM;

    float acc[8];
#pragma unroll
    for (int e = 0; e < 8; e++) acc[e] = 0.f;
#pragma unroll
    for (int i = 0; i < 4; i++) {
      const int off = i * 256 + lane * 4;
      float4 xv = *(const float4*)(x + off);
#pragma unroll
      for (int e = 0; e < 8; e++) {
        float4 wv = *(const float4*)(Wg + e * IN_DIM + off);
        acc[e] += xv.x * wv.x + xv.y * wv.y + xv.z * wv.z + xv.w * wv.w;
      }
    }
#pragma unroll
    for (int e = 0; e < 8; e++) {
#pragma unroll
      for (int m = 32; m >= 1; m >>= 1)
        acc[e] += __shfl_xor(acc[e], m);
      acc[e] += bg[e];
    }
    if (lane == 0) {
      int i0 = 0; float v0 = acc[0];
#pragma unroll
      for (int e = 1; e < 8; e++) if (acc[e] > v0) { v0 = acc[e]; i0 = e; }
      int i1 = -1; float v1 = -3.4e38f;
#pragma unroll
      for (int e = 0; e < 8; e++) if (e != i0 && acc[e] > v1) { v1 = acc[e]; i1 = e; }
      float e1 = __expf(v1 - v0);
      float inv = 1.f / (1.f + e1);
      gate[row] = make_float4(__int_as_float(i0), __int_as_float(i1), inv, e1 * inv);
    }
  }
}

// ---------------- GEMM ----------------
__global__ __launch_bounds__(256) void gemm_kernel(
    const short* __restrict__ Xbf,
    const short* __restrict__ Wbf,
    const float* __restrict__ bb,
    float* __restrict__ Y)
{
  __shared__ short As[128 * 32];
  __shared__ short Bs[128 * 32];

  const int tid  = threadIdx.x;
  const int lane = tid & 63;
  const int wv   = tid >> 6;
  const int quad = lane >> 4;
  const int cl   = lane & 15;
  const int wm   = wv & 1;
  const int wn   = wv >> 1;
  const int m0 = blockIdx.y * 128;
  const int n0 = blockIdx.x * 128;

  const int srow = wv * 32 + (lane >> 2);
  const int scol = (lane & 3) * 8;
  const short* gA = Xbf + (int64_t)(m0 + srow) * IN_DIM + scol;
  const short* gB = Wbf + (int64_t)(n0 + srow) * IN_DIM + scol;
  short* lA = As + (wv * 32) * 32;
  short* lB = Bs + (wv * 32) * 32;

  floatx4 acc[4][4];
#pragma unroll
  for (int i = 0; i < 4; i++)
#pragma unroll
    for (int k = 0; k < 4; k++) acc[i][k] = (floatx4){0.f, 0.f, 0.f, 0.f};

  for (int ks = 0; ks < IN_DIM; ks += 32) {
    gl_lds16(gA + ks,                lA);
    gl_lds16(gA + 16 * IN_DIM + ks,  lA + 16 * 32);
    gl_lds16(gB + ks,                lB);
    gl_lds16(gB + 16 * IN_DIM + ks,  lB + 16 * 32);
    __syncthreads();

    short8 bfrag[4], afrag[4];
#pragma unroll
    for (int nt = 0; nt < 4; nt++)
      bfrag[nt] = *(const short8*)(&Bs[(wn * 64 + nt * 16 + cl) * 32 + quad * 8]);
#pragma unroll
    for (int mt = 0; mt < 4; mt++)
      afrag[mt] = *(const short8*)(&As[(wm * 64 + mt * 16 + cl) * 32 + quad * 8]);
#pragma unroll
    for (int mt = 0; mt < 4; mt++)
#pragma unroll
      for (int nt = 0; nt < 4; nt++)
        acc[mt][nt] = __builtin_amdgcn_mfma_f32_16x16x32_bf16(afrag[mt], bfrag[nt], acc[mt][nt], 0, 0, 0);
    __syncthreads();
  }

#pragma unroll
  for (int nt = 0; nt < 4; nt++) {
    const int col = n0 + wn * 64 + nt * 16 + cl;
    const float bias = bb[col];
#pragma unroll
    for (int mt = 0; mt < 4; mt++) {
#pragma unroll
      for (int r = 0; r < 4; r++) {
        int row = m0 + wm * 64 + mt * 16 + quad * 4 + r;
        Y[(int64_t)row * NPAD + col] = acc[mt][nt][r] + bias;
      }
    }
  }
}

// ---------------- pack: gather + bf16-compress into 928B records ----------------
__global__ __launch_bounds__(256) void pack_kernel(
    const float* __restrict__ Y, const float4* __restrict__ gate,
    uint32_t* __restrict__ Ypk)
{
  const int row  = blockIdx.x * 4 + (threadIdx.x >> 6);
  const int lane = threadIdx.x & 63;
  const float* Yp = Y + (int64_t)row * NPAD;
  uint32_t* Pp = Ypk + (int64_t)row * PKROW_D;
  float4 g = gate[row];
  const int i0 = __float_as_int(g.x), i1 = __float_as_int(g.y);

  if (lane < 56) {
    const int seg = lane >> 3;          // 0:k0 1:ka 2:kb 3:q 4:v0 5:va 6:vb
    const int f0  = (lane & 7) * 8;
    const int slot = (seg == 1 || seg == 5) ? i0 : ((seg == 2 || seg == 6) ? i1 : 0);
    const int base = (seg == 3) ? 1152 : (((seg >= 4) ? 576 : 0) + 64 * slot);
    float4 a = *(const float4*)(Yp + base + f0);
    float4 bq4 = *(const float4*)(Yp + base + f0 + 4);
    short8 s;
    s[0]=f2bf(a.x); s[1]=f2bf(a.y); s[2]=f2bf(a.z); s[3]=f2bf(a.w);
    s[4]=f2bf(bq4.x); s[5]=f2bf(bq4.y); s[6]=f2bf(bq4.z); s[7]=f2bf(bq4.w);
    *(short8*)(Pp + lane * 4) = s;
  } else if (lane == 56) {
    *(float4*)(Pp + 224) = g;           // gate fp32 raw @ dword 224
  }
}

// 16-lane (DPP row) sum; result valid in lane (lane&15)==15.
static __device__ __forceinline__ float row16_sum(float x) {
  float r = x;
  r += __int_as_float(__builtin_amdgcn_update_dpp(0, __float_as_int(r), 0x118, 0xf, 0xf, false));
  r += __int_as_float(__builtin_amdgcn_update_dpp(0, __float_as_int(r), 0x114, 0xf, 0xf, false));
  r += __int_as_float(__builtin_amdgcn_update_dpp(0, __float_as_int(r), 0x112, 0xf, 0xf, false));
  r += __int_as_float(__builtin_amdgcn_update_dpp(0, __float_as_int(r), 0x111, 0xf, 0xf, false));
  return r;
}

// ======================= chunked scan-from-zero =======================
// R15 post-mortem: full residency (20 waves/CU) did NOT reduce dur — stall is
// ~300 cyc/wave-step invariant to all data-side changes. Revised theory:
// INSTRUCTION-FETCH bound. The fully-unrolled 8-step body with two 8-way
// switches per step is ~33 KB — exceeds the 32 KB I-cache; every tile
// iteration re-streams the body from L2. R16: #pragma unroll 2 on the step
// loop (~9 KB body, fits I-cache). Everything else identical to R15.

#define STAGE_TILE(TBASE, DST) {                                     \
    const int trow = (TBASE) + srow_;                                \
    const uint32_t* Pp = Ypk + (int64_t)(trow * BATCH + b) * PKROW_D;\
    uint32_t* dbuf = sY + (DST) * TILEF_D + srow_ * TROW_D;          \
    _Pragma("unroll")                                                \
    for (int kq = 0; kq < 4; kq++) {                                 \
      const int idx = rtid_ + 16 * kq;                               \
      if (idx < 57)                                                  \
        *(uint4*)(dbuf + idx * 4) = *(const uint4*)(Pp + idx * 4);   \
    } }

#define UNPACK_STEP_COMMON                                           \
    float4 gl = *(const float4*)(rb + 224);                          \
    uint2 uk0 = *(const uint2*)(rb + igrp * 2);                      \
    uint2 uka = *(const uint2*)(rb + 32 + igrp * 2);                 \
    uint2 ukb = *(const uint2*)(rb + 64 + igrp * 2);                 \
    uint32_t pv0 = rb[128 + jv], pva = rb[160 + jv], pvb = rb[192 + jv]; \
    const int i0 = __float_as_int(gl.x);                             \
    const int i1 = __float_as_int(gl.y);                             \
    float k00=bflo(uk0.x),k01=bfhi(uk0.x),k02=bflo(uk0.y),k03=bfhi(uk0.y); \
    float ka0=bflo(uka.x),ka1=bfhi(uka.x),ka2=bflo(uka.y),ka3=bfhi(uka.y); \
    float kb0=bflo(ukb.x),kb1=bfhi(ukb.x),kb2=bflo(ukb.y),kb3=bfhi(ukb.y); \
    float v0a=bflo(pv0), v0b=bfhi(pv0);                              \
    float vaa=bflo(pva), vab=bfhi(pva);                              \
    float vba=bflo(pvb), vbb=bfhi(pvb);

// ---------------- scan: local recurrence from zero; writes o_local and ΔM(bf16) ----------------
__global__ __launch_bounds__(128) void chunk_scan_kernel(
    const uint32_t* __restrict__ Ypk,
    uint32_t* __restrict__ DMh,      // OUT: packed-bf16 ΔM per (c,b)
    float* __restrict__ out)
{
  __shared__ uint32_t sY[2 * TILEF_D];
  const int blk  = blockIdx.x;
  const int c    = blk & 15;
  const int rest = blk >> 4;
  const int jq   = rest & 3;               // j quarter (16 j)
  const int b    = rest >> 2;
  const int tid  = threadIdx.x;            // 0..127 (2 waves)
  const int lane = tid & 63;
  const int wvv  = tid >> 6;               // 0..1
  const int igrp = lane & 15;
  const int jp   = wvv * 4 + (lane >> 4);  // 0..7
  const int j0   = jq * 16 + jp * 2;
  const int jv   = jq * 8 + jp;            // v dword / jpair index
  const int ib   = igrp * 4;
  const int srow_ = tid >> 4;              // 0..7
  const int rtid_ = tid & 15;
  const int t0   = c * CHL;

  float M[9][4][2];
#pragma unroll
  for (int m = 0; m < 9; m++)
#pragma unroll
    for (int ii = 0; ii < 4; ii++) { M[m][ii][0] = 0.f; M[m][ii][1] = 0.f; }

#define DO_SLOT(mm, gw, K0_,K1_,K2_,K3_, Va_, Vb_) {                 \
    M[mm][0][0] += K0_*Va_; M[mm][1][0] += K1_*Va_;                  \
    M[mm][2][0] += K2_*Va_; M[mm][3][0] += K3_*Va_;                  \
    M[mm][0][1] += K0_*Vb_; M[mm][1][1] += K1_*Vb_;                  \
    M[mm][2][1] += K2_*Vb_; M[mm][3][1] += K3_*Vb_;                  \
    Mc00 += (gw)*M[mm][0][0]; Mc10 += (gw)*M[mm][1][0];              \
    Mc20 += (gw)*M[mm][2][0]; Mc30 += (gw)*M[mm][3][0];              \
    Mc01 += (gw)*M[mm][0][1]; Mc11 += (gw)*M[mm][1][1];              \
    Mc21 += (gw)*M[mm][2][1]; Mc31 += (gw)*M[mm][3][1]; }

#define DO_SLOT0(gw, K0_,K1_,K2_,K3_, Va_, Vb_) {                    \
    float d00=K0_*Va_, d10=K1_*Va_, d20=K2_*Va_, d30=K3_*Va_;        \
    float d01=K0_*Vb_, d11=K1_*Vb_, d21=K2_*Vb_, d31=K3_*Vb_;        \
    M[0][0][0]+=d00; M[0][1][0]+=d10; M[0][2][0]+=d20; M[0][3][0]+=d30; \
    M[0][0][1]+=d01; M[0][1][1]+=d11; M[0][2][1]+=d21; M[0][3][1]+=d31; \
    Mc00 += d00 + (gw)*M[0][0][0]; Mc10 += d10 + (gw)*M[0][1][0];    \
    Mc20 += d20 + (gw)*M[0][2][0]; Mc30 += d30 + (gw)*M[0][3][0];    \
    Mc01 += d01 + (gw)*M[0][0][1]; Mc11 += d11 + (gw)*M[0][1][1];    \
    Mc21 += d21 + (gw)*M[0][2][1]; Mc31 += d31 + (gw)*M[0][3][1]; }

#define CSTEP_C(P, R, TT) {                                          \
    const uint32_t* rb = sY + (P) * TILEF_D + (R) * TROW_D;          \
    UNPACK_STEP_COMMON                                               \
    uint2 uq = *(const uint2*)(rb + 96 + igrp * 2);                  \
    float q0=bflo(uq.x),q1=bfhi(uq.x),q2=bflo(uq.y),q3=bfhi(uq.y);   \
    const float g0w = gl.z, g1w = gl.w;                              \
    M[0][0][0]+=k00*v0a; M[0][1][0]+=k01*v0a;                        \
    M[0][2][0]+=k02*v0a; M[0][3][0]+=k03*v0a;                        \
    M[0][0][1]+=k00*v0b; M[0][1][1]+=k01*v0b;                        \
    M[0][2][1]+=k02*v0b; M[0][3][1]+=k03*v0b;                        \
    float Mc00=M[0][0][0], Mc10=M[0][1][0], Mc20=M[0][2][0], Mc30=M[0][3][0]; \
    float Mc01=M[0][0][1], Mc11=M[0][1][1], Mc21=M[0][2][1], Mc31=M[0][3][1]; \
    switch (i0) {                                                    \
      case 0: DO_SLOT0(g0w, ka0,ka1,ka2,ka3, vaa, vab); break;       \
      case 1: DO_SLOT(1, g0w, ka0,ka1,ka2,ka3, vaa, vab); break;     \
      case 2: DO_SLOT(2, g0w, ka0,ka1,ka2,ka3, vaa, vab); break;     \
      case 3: DO_SLOT(3, g0w, ka0,ka1,ka2,ka3, vaa, vab); break;     \
      case 4: DO_SLOT(4, g0w, ka0,ka1,ka2,ka3, vaa, vab); break;     \
      case 5: DO_SLOT(5, g0w, ka0,ka1,ka2,ka3, vaa, vab); break;     \
      case 6: DO_SLOT(6, g0w, ka0,ka1,ka2,ka3, vaa, vab); break;     \
      default: DO_SLOT(7, g0w, ka0,ka1,ka2,ka3, vaa, vab); break;    \
    }                                                                \
    switch (i1) {                                                    \
      case 0: DO_SLOT0(g1w, kb0,kb1,kb2,kb3, vba, vbb); break;       \
      case 1: DO_SLOT(1, g1w, kb0,kb1,kb2,kb3, vba, vbb); break;     \
      case 2: DO_SLOT(2, g1w, kb0,kb1,kb2,kb3, vba, vbb); break;     \
      case 3: DO_SLOT(3, g1w, kb0,kb1,kb2,kb3, vba, vbb); break;     \
      case 4: DO_SLOT(4, g1w, kb0,kb1,kb2,kb3, vba, vbb); break;     \
      case 5: DO_SLOT(5, g1w, kb0,kb1,kb2,kb3, vba, vbb); break;     \
      case 6: DO_SLOT(6, g1w, kb0,kb1,kb2,kb3, vba, vbb); break;     \
      default: DO_SLOT(7, g1w, kb0,kb1,kb2,kb3, vba, vbb); break;    \
    }                                                                \
    float p0 = q0*Mc00 + q1*Mc10 + q2*Mc20 + q3*Mc30;                \
    float p1 = q0*Mc01 + q1*Mc11 + q2*Mc21 + q3*Mc31;                \
    p0 = row16_sum(p0); p1 = row16_sum(p1);                          \
    if (igrp == 15) {                                                \
      out[(int64_t)(TT) * (BATCH * HID) + b * HID + j0]     = p0;    \
      out[(int64_t)(TT) * (BATCH * HID) + b * HID + j0 + 1] = p1;    \
    } }

  STAGE_TILE(t0, 0);

  for (int tile = 0; tile < NTILE; ++tile) {
    const int p = tile & 1;
    __syncthreads();
#pragma unroll 2
    for (int r = 0; r < 8; r++) CSTEP_C(p, r, t0 + tile * 8 + r);   // I-cache fix: body ~9KB
    if (tile + 1 < NTILE) STAGE_TILE(t0 + (tile + 1) * 8, p ^ 1);
  }
#undef CSTEP_C
#undef DO_SLOT
#undef DO_SLOT0

  // ΔM writeout, packed bf16 pair per (m,i)
  uint32_t* dmb = DMh + ((int64_t)(c * 32 + b)) * DM_CB;
#pragma unroll
  for (int m = 0; m < 9; m++)
#pragma unroll
    for (int ii = 0; ii < 4; ii++)
      dmb[m * 2048 + (ib + ii) * 32 + jv] = pk2bf(M[m][ii][0], M[m][ii][1]);
}

// ---------------- prefix: ΔM(bf16) -> Mstart(bf16) exclusive +M0; writes M_final fp32 ----------------
__global__ void prefix_kernel(const float* __restrict__ M0, uint32_t* __restrict__ DMh,
                              float* __restrict__ out, int nc)
{
  int64_t e = (int64_t)blockIdx.x * blockDim.x + threadIdx.x;   // < 32*18432 u32 units
  int b = (int)(e / DM_CB);
  int r = (int)(e % DM_CB);                 // m*2048 + i*32 + jpair
  int m = r >> 11, rem = r & 2047, i = rem >> 5, jp = rem & 31;
  int64_t f32i = (int64_t)b * 36864 + m * 4096 + i * 64 + jp * 2;
  float run0 = M0[f32i], run1 = M0[f32i + 1];
  for (int cc = 0; cc < nc; cc++) {
    int64_t idx = ((int64_t)(cc * 32 + b)) * DM_CB + r;
    uint32_t u = DMh[idx];
    DMh[idx] = pk2bf(run0, run1);
    run0 += bflo(u); run1 += bfhi(u);
  }
  *(float2*)(out + (int64_t)SEQ * BATCH * HID + f32i) = make_float2(run0, run1);
}

// ---------------- corr: o += q·(Mstart[0] + g0·Mstart[i0] + g1·Mstart[i1]) ----------------
// block = (b,c,jh): Mstart j-half (bf16, direct copy) in LDS [m][i][jj], q bf16, gates.
__global__ __launch_bounds__(256) void corr_kernel(
    const uint32_t* __restrict__ Ypk, const float4* __restrict__ gate,
    const uint32_t* __restrict__ DMh, float* __restrict__ out)
{
  __shared__ uint32_t Msb32[9 * 64 * 16];   // bf16 pairs [m][i][jpair-half] = 36.9KB
  __shared__ uint32_t qb[CHL * 32];         // q bf16 pairs [t][i/2]
  __shared__ float4 gl[CHL];
  unsigned short* Msb = (unsigned short*)Msb32;
  const int blk = blockIdx.x;
  const int c   = blk & 15;
  const int jh  = (blk >> 4) & 1;
  const int b   = blk >> 5;
  const int tid = threadIdx.x;
  const int t0  = c * CHL;

  if (tid < CHL) gl[tid] = gate[(t0 + tid) * BATCH + b];
#pragma unroll
  for (int k = 0; k < 2; k++) {
    int f = tid + 256 * k;                // < 512
    int t = f >> 5, dd = f & 31;
    qb[t * 32 + dd] = Ypk[(int64_t)((t0 + t) * BATCH + b) * PKROW_D + 96 + dd];
  }
  const uint32_t* dmb = DMh + ((int64_t)(c * 32 + b)) * DM_CB;
#pragma unroll
  for (int k = 0; k < 36; k++) {
    int f = tid + 256 * k;                // < 9216 u32
    int m = f >> 10, rem = f & 1023, i = rem >> 4, p = rem & 15;
    Msb32[(m * 64 + i) * 16 + p] = dmb[m * 2048 + i * 32 + jh * 16 + p];
  }
  __syncthreads();

  const int jj = tid & 31;
  const int tg = tid >> 5;
#pragma unroll
  for (int tt = 0; tt < CHL / 8; tt++) {
    const int t = tt * 8 + tg;
    float4 g = gl[t];
    const int i0 = __float_as_int(g.x), i1 = __float_as_int(g.y);
    const float g0 = g.z, g1 = g.w;
    float acc = 0.f;
#pragma unroll 8
    for (int i2 = 0; i2 < 32; i2++) {
      uint32_t uq = qb[t * 32 + i2];
      float q0 = bflo(uq), q1 = bfhi(uq);
      int ia = 2 * i2;
      float m0a = bfu(Msb[(0  * 64 + ia) * 32 + jj]);
      float m0b = bfu(Msb[(0  * 64 + ia + 1) * 32 + jj]);
      float maa = bfu(Msb[(i0 * 64 + ia) * 32 + jj]);
      float mab = bfu(Msb[(i0 * 64 + ia + 1) * 32 + jj]);
      float mba = bfu(Msb[(i1 * 64 + ia) * 32 + jj]);
      float mbb = bfu(Msb[(i1 * 64 + ia + 1) * 32 + jj]);
      acc += q0 * (m0a + g0 * maa + g1 * mba);
      acc += q1 * (m0b + g0 * mab + g1 * mbb);
    }
    float* op = out + (int64_t)(t0 + t) * (BATCH * HID) + b * HID + jh * 32 + jj;
    *op += acc;
  }
}

// ---------------- launch ----------------
extern "C" void kernel_launch(void* const* d_in, const int* in_sizes, int n_in,
                              void* d_out, int out_size, void* d_ws, size_t ws_size,
                              hipStream_t stream)
{
  const float* X  = (const float*)d_in[0];
  const float* M0 = (const float*)d_in[1];
  const float* Wk = (const float*)d_in[2];
  const float* bk = (const float*)d_in[3];
  const float* Wv = (const float*)d_in[4];
  const float* bv = (const float*)d_in[5];
  const float* Wg = (const float*)d_in[6];
  const float* bg = (const float*)d_in[7];
  const float* Wq = (const float*)d_in[8];
  const float* bq = (const float*)d_in[9];

  char* ws = (char*)d_ws;
  short*    Xbf  = (short*)(ws + XBF_OFF);
  short*    Wbf  = (short*)(ws + WBF_OFF);
  float*    bb   = (float*)(ws + BB_OFF);
  float4*   gate = (float4*)(ws + GATE_OFF);
  float*    Y    = (float*)(ws + Y_OFF);
  uint32_t* Ypk  = (uint32_t*)(ws + YPK_OFF);  // overlays Xbf (dead after gemm)
  uint32_t* DMh  = (uint32_t*)(ws + DM_OFF);   // overlays Y   (dead after pack)
  float*    out  = (float*)d_out;

  prep_gate_kernel<<<4096, 256, 0, stream>>>(X, Wk, bk, Wv, bv, Wg, bg, Wq, bq,
                                             Xbf, Wbf, bb, gate);
  dim3 gg(NPAD / 128, ROWS / 128);
  gemm_kernel<<<gg, 256, 0, stream>>>(Xbf, Wbf, bb, Y);
  pack_kernel<<<ROWS / 4, 256, 0, stream>>>(Y, gate, Ypk);
  chunk_scan_kernel<<<32 * NC * 4, 128, 0, stream>>>(Ypk, DMh, out);
  prefix_kernel<<<(32 * DM_CB) / 256, 256, 0, stream>>>(M0, DMh, out, NC);
  corr_kernel<<<32 * NC * 2, 256, 0, stream>>>(Ypk, gate, DMh, out);
}

// Round 17
// 183.328 us; speedup vs baseline: 1.2184x; 1.2184x over previous
//
#include <hip/hip_runtime.h>
#include <stdint.h>

#define SEQ 256
#define BATCH 32
#define IN_DIM 1024
#define HID 64
#define NPAD 1280
#define ROWS (SEQ*BATCH)   // 8192

// workspace layout (high-water 61,477,888 B — proven footprint):
//  [0,16.78M)      Xbf (prep->gemm), then DMh bf16 ΔM/Mstart [18.87 MB, spills into
//  [16.78M,19.40M) Wbf               dead Wbf region; ends 18,874,368 < bb @19,398,656]
//  [19.40M,..)     bb, gate (live throughout)
//  [19.53M,61.48M) Y (gemm -> mfma_chunk/corr; stays live, no overlay)
#define XBF_OFF   0
#define DMH_OFF   0
#define WBF_OFF   16777216
#define BB_OFF    19398656
#define GATE_OFF  19403776
#define Y_OFF     19534848

#define NC 8
#define CHL 32      // chunk length; 96 triples per (b,c)

// DMh: per (c,b): bf16 [m(9)][i(64)][j(64)] = 36864 u16 = 73.7 KB; total 8*32 = 18.87 MB
#define DM_CB_U32 18432

typedef __attribute__((ext_vector_type(8))) short short8;
typedef __attribute__((ext_vector_type(4))) float floatx4;

typedef const __attribute__((address_space(1))) unsigned int gas_u32;
typedef __attribute__((address_space(3))) unsigned int las_u32;
static __device__ __forceinline__ void gl_lds16(const void* g, void* l) {
  __builtin_amdgcn_global_load_lds((gas_u32*)g, (las_u32*)l, 16, 0, 0);
}

static __device__ __forceinline__ short f2bf(float f) {
  union { float f; uint32_t u; } a; a.f = f;
  uint32_t r = (a.u + 0x7FFFu + ((a.u >> 16) & 1u)) >> 16;  // RNE
  return (short)r;
}
static __device__ __forceinline__ float bflo(uint32_t u){ return __uint_as_float(u << 16); }
static __device__ __forceinline__ float bfhi(uint32_t u){ return __uint_as_float(u & 0xffff0000u); }
static __device__ __forceinline__ float bfu(unsigned short us){ return __uint_as_float(((uint32_t)us) << 16); }

// ---------------- fused prep + gate ----------------
__global__ __launch_bounds__(256) void prep_gate_kernel(
    const float* __restrict__ X,
    const float* __restrict__ Wk, const float* __restrict__ bk,
    const float* __restrict__ Wv, const float* __restrict__ bv,
    const float* __restrict__ Wg, const float* __restrict__ bg,
    const float* __restrict__ Wq, const float* __restrict__ bq,
    short* __restrict__ Xbf, short* __restrict__ Wbf,
    float* __restrict__ bb, float4* __restrict__ gate)
{
  if (blockIdx.x < 2048) {
    int64_t idx = (int64_t)blockIdx.x * blockDim.x + threadIdx.x;
    int64_t stride = (int64_t)2048 * 256;
    const int64_t NX4 = (int64_t)ROWS * IN_DIM / 4;
    for (int64_t i = idx; i < NX4; i += stride) {
      float4 x = ((const float4*)X)[i];
      short4 s4;
      s4.x = f2bf(x.x); s4.y = f2bf(x.y); s4.z = f2bf(x.z); s4.w = f2bf(x.w);
      ((short4*)Xbf)[i] = s4;
    }
    const int64_t NW4 = (int64_t)NPAD * IN_DIM / 4;
    for (int64_t i = idx; i < NW4; i += stride) {
      int64_t e = i * 4;
      int r = (int)(e >> 10);
      int k = (int)(e & 1023);
      float4 x;
      if (r < 576)       x = *(const float4*)(Wk + (int64_t)r*1024 + k);
      else if (r < 1152) x = *(const float4*)(Wv + (int64_t)(r-576)*1024 + k);
      else if (r < 1216) x = *(const float4*)(Wq + (int64_t)(r-1152)*1024 + k);
      else               x = make_float4(0.f, 0.f, 0.f, 0.f);
      short4 s4;
      s4.x = f2bf(x.x); s4.y = f2bf(x.y); s4.z = f2bf(x.z); s4.w = f2bf(x.w);
      ((short4*)Wbf)[i] = s4;
    }
    for (int64_t i = idx; i < NPAD; i += stride) {
      int r = (int)i; float v;
      if (r < 576)       v = bk[r];
      else if (r < 1152) v = bv[r - 576];
      else if (r < 1216) v = bq[r - 1152];
      else               v = 0.f;
      bb[r] = v;
    }
  } else {
    const int lane = threadIdx.x & 63;
    const int row  = (blockIdx.x - 2048) * 4 + (threadIdx.x >> 6);
    const float* x = X + (int64_t)row * IN_DIM;

    float acc[8];
#pragma unroll
    for (int e = 0; e < 8; e++) acc[e] = 0.f;
#pragma unroll
    for (int i = 0; i < 4; i++) {
      const int off = i * 256 + lane * 4;
      float4 xv = *(const float4*)(x + off);
#pragma unroll
      for (int e = 0; e < 8; e++) {
        float4 wv = *(const float4*)(Wg + e * IN_DIM + off);
        acc[e] += xv.x * wv.x + xv.y * wv.y + xv.z * wv.z + xv.w * wv.w;
      }
    }
#pragma unroll
    for (int e = 0; e < 8; e++) {
#pragma unroll
      for (int m = 32; m >= 1; m >>= 1)
        acc[e] += __shfl_xor(acc[e], m);
      acc[e] += bg[e];
    }
    if (lane == 0) {
      int i0 = 0; float v0 = acc[0];
#pragma unroll
      for (int e = 1; e < 8; e++) if (acc[e] > v0) { v0 = acc[e]; i0 = e; }
      int i1 = -1; float v1 = -3.4e38f;
#pragma unroll
      for (int e = 0; e < 8; e++) if (e != i0 && acc[e] > v1) { v1 = acc[e]; i1 = e; }
      float e1 = __expf(v1 - v0);
      float inv = 1.f / (1.f + e1);
      gate[row] = make_float4(__int_as_float(i0), __int_as_float(i1), inv, e1 * inv);
    }
  }
}

// ---------------- GEMM (unchanged, verified) ----------------
__global__ __launch_bounds__(256) void gemm_kernel(
    const short* __restrict__ Xbf,
    const short* __restrict__ Wbf,
    const float* __restrict__ bb,
    float* __restrict__ Y)
{
  __shared__ short As[128 * 32];
  __shared__ short Bs[128 * 32];

  const int tid  = threadIdx.x;
  const int lane = tid & 63;
  const int wv   = tid >> 6;
  const int quad = lane >> 4;
  const int cl   = lane & 15;
  const int wm   = wv & 1;
  const int wn   = wv >> 1;
  const int m0 = blockIdx.y * 128;
  const int n0 = blockIdx.x * 128;

  const int srow = wv * 32 + (lane >> 2);
  const int scol = (lane & 3) * 8;
  const short* gA = Xbf + (int64_t)(m0 + srow) * IN_DIM + scol;
  const short* gB = Wbf + (int64_t)(n0 + srow) * IN_DIM + scol;
  short* lA = As + (wv * 32) * 32;
  short* lB = Bs + (wv * 32) * 32;

  floatx4 acc[4][4];
#pragma unroll
  for (int i = 0; i < 4; i++)
#pragma unroll
    for (int k = 0; k < 4; k++) acc[i][k] = (floatx4){0.f, 0.f, 0.f, 0.f};

  for (int ks = 0; ks < IN_DIM; ks += 32) {
    gl_lds16(gA + ks,                lA);
    gl_lds16(gA + 16 * IN_DIM + ks,  lA + 16 * 32);
    gl_lds16(gB + ks,                lB);
    gl_lds16(gB + 16 * IN_DIM + ks,  lB + 16 * 32);
    __syncthreads();

    short8 bfrag[4], afrag[4];
#pragma unroll
    for (int nt = 0; nt < 4; nt++)
      bfrag[nt] = *(const short8*)(&Bs[(wn * 64 + nt * 16 + cl) * 32 + quad * 8]);
#pragma unroll
    for (int mt = 0; mt < 4; mt++)
      afrag[mt] = *(const short8*)(&As[(wm * 64 + mt * 16 + cl) * 32 + quad * 8]);
#pragma unroll
    for (int mt = 0; mt < 4; mt++)
#pragma unroll
      for (int nt = 0; nt < 4; nt++)
        acc[mt][nt] = __builtin_amdgcn_mfma_f32_16x16x32_bf16(afrag[mt], bfrag[nt], acc[mt][nt], 0, 0, 0);
    __syncthreads();
  }

#pragma unroll
  for (int nt = 0; nt < 4; nt++) {
    const int col = n0 + wn * 64 + nt * 16 + cl;
    const float bias = bb[col];
#pragma unroll
    for (int mt = 0; mt < 4; mt++) {
#pragma unroll
      for (int r = 0; r < 4; r++) {
        int row = m0 + wm * 64 + mt * 16 + quad * 4 + r;
        Y[(int64_t)row * NPAD + col] = acc[mt][nt][r] + bias;
      }
    }
  }
}

// ======================= MFMA chunk kernel =======================
// Per (b,c): 96 triples e=3s+u with head/slot u in {0,i0(s),i1(s)}.
//  S = Q K^T (32x96), P = W .* S with W(t,e)=[s(e)<=t]*rw(t,slot(e)),
//  o_local = P V (32x64), dM[m] = K^T diag(slot==m) V (9x 64x64).
// Frag layouts identical to gemm_kernel (A/B: [row][k], row=lane&15, k=quad*8+j;
// C: row=quad*4+reg, col=lane&15). P goes C-layout -> LDS -> A-layout.
__global__ __launch_bounds__(256) void mfma_chunk_kernel(
    const float* __restrict__ Y, const float4* __restrict__ gate,
    unsigned short* __restrict__ DMu, float* __restrict__ out)
{
  __shared__ uint32_t Qs[32 * 32];          // bf16 pairs [t][dpair]
  __shared__ uint32_t Ks[96 * 32];          // bf16 pairs [e][dpair]
  __shared__ unsigned short Kts[64 * 104];  // K^T [d][e], pad 96->104
  __shared__ unsigned short Vts[64 * 104];  // V^T [d][e]
  __shared__ unsigned short Ps[32 * 104];   // P   [t][e]
  __shared__ float4 gl[32];
  __shared__ uint32_t su[96];               // slot of triple e

  const int blk = blockIdx.x;
  const int c   = blk & 7;
  const int b   = blk >> 3;
  const int tid = threadIdx.x;
  const int lane = tid & 63;
  const int wv  = tid >> 6;
  const int quad = lane >> 4;
  const int cl  = lane & 15;
  const int t0  = c * CHL;

  // ---- stage gates + slot ids ----
  if (tid < 32) {
    float4 g = gate[(t0 + tid) * BATCH + b];
    gl[tid] = g;
    su[3 * tid]     = 0u;
    su[3 * tid + 1] = (uint32_t)__float_as_int(g.x);
    su[3 * tid + 2] = (uint32_t)__float_as_int(g.y);
  }
  __syncthreads();

  // ---- stage K (natural + transposed), V (transposed), Q — gathered from Y via gates ----
  for (int idx = tid; idx < 3072; idx += 256) {      // e = idx>>5, dpair = idx&31
    const int e = idx >> 5, dd = idx & 31;
    const int s = (e * 171) >> 9;                    // e/3 (exact for e<96)
    const int u = e - 3 * s;
    const int head = (u == 0) ? 0 : (int)su[3 * s + u];
    const float* Yr = Y + ((int64_t)(t0 + s) * BATCH + b) * NPAD;
    float f0 = Yr[head * 64 + 2 * dd], f1 = Yr[head * 64 + 2 * dd + 1];
    unsigned short b0 = (unsigned short)f2bf(f0), b1 = (unsigned short)f2bf(f1);
    Ks[e * 32 + dd] = (uint32_t)b0 | ((uint32_t)b1 << 16);
    Kts[(2 * dd) * 104 + e] = b0;
    Kts[(2 * dd + 1) * 104 + e] = b1;
    float v0 = Yr[576 + head * 64 + 2 * dd], v1 = Yr[576 + head * 64 + 2 * dd + 1];
    Vts[(2 * dd) * 104 + e] = (unsigned short)f2bf(v0);
    Vts[(2 * dd + 1) * 104 + e] = (unsigned short)f2bf(v1);
  }
  for (int idx = tid; idx < 1024; idx += 256) {      // t = idx>>5, dpair = idx&31
    const int s = idx >> 5, dd = idx & 31;
    const float* Yr = Y + ((int64_t)(t0 + s) * BATCH + b) * NPAD;
    Qs[s * 32 + dd] = ((uint32_t)(unsigned short)f2bf(Yr[1152 + 2 * dd])) |
                      (((uint32_t)(unsigned short)f2bf(Yr[1152 + 2 * dd + 1])) << 16);
  }
  __syncthreads();

  const unsigned short* Qu = (const unsigned short*)Qs;
  const unsigned short* Ku = (const unsigned short*)Ks;

  // ---- phase S + weight + pack P : 12 C-tiles, 3 per wave ----
#pragma unroll
  for (int q3 = 0; q3 < 3; q3++) {
    const int tileId = wv * 3 + q3;           // 0..11
    const int mt = tileId / 6, nt = tileId % 6;
    floatx4 acc = (floatx4){0.f, 0.f, 0.f, 0.f};
#pragma unroll
    for (int kc = 0; kc < 2; kc++) {
      short8 af = *(const short8*)(Qu + (mt * 16 + cl) * 64 + kc * 32 + quad * 8);
      short8 bf = *(const short8*)(Ku + (nt * 16 + cl) * 64 + kc * 32 + quad * 8);
      acc = __builtin_amdgcn_mfma_f32_16x16x32_bf16(af, bf, acc, 0, 0, 0);
    }
    const int e = nt * 16 + cl;
    const int s_e = (e * 171) >> 9;
    const int slot_e = (int)su[e];
#pragma unroll
    for (int r = 0; r < 4; r++) {
      const int t = mt * 16 + quad * 4 + r;
      float4 g = gl[t];
      const int i0t = __float_as_int(g.x), i1t = __float_as_int(g.y);
      float w = (slot_e == 0 ? 1.f : 0.f)
              + (slot_e == i0t ? g.z : 0.f)
              + (slot_e == i1t ? g.w : 0.f);
      w = (s_e <= t) ? w : 0.f;
      Ps[t * 104 + e] = (unsigned short)f2bf(w * acc[r]);
    }
  }
  __syncthreads();

  // ---- phase PV : o_local = P V, 8 C-tiles, 2 per wave ----
#pragma unroll
  for (int q2 = 0; q2 < 2; q2++) {
    const int tileId = wv + q2 * 4;           // 0..7
    const int mt = tileId >> 2, nt = tileId & 3;
    floatx4 acc = (floatx4){0.f, 0.f, 0.f, 0.f};
#pragma unroll
    for (int kc = 0; kc < 3; kc++) {
      short8 af = *(const short8*)(Ps  + (mt * 16 + cl) * 104 + kc * 32 + quad * 8);
      short8 bf = *(const short8*)(Vts + (nt * 16 + cl) * 104 + kc * 32 + quad * 8);
      acc = __builtin_amdgcn_mfma_f32_16x16x32_bf16(af, bf, acc, 0, 0, 0);
    }
#pragma unroll
    for (int r = 0; r < 4; r++) {
      const int t = mt * 16 + quad * 4 + r, j = nt * 16 + cl;
      out[(int64_t)(t0 + t) * (BATCH * HID) + b * HID + j] = acc[r];
    }
  }

  // ---- phase dM : per slot m, D = K^T diag(slot==m) V ----
  uint32_t sreg[3][8];
#pragma unroll
  for (int kc = 0; kc < 3; kc++)
#pragma unroll
    for (int jj = 0; jj < 8; jj++)
      sreg[kc][jj] = su[kc * 32 + quad * 8 + jj];

  short8 afc[4][3];
#pragma unroll
  for (int mt = 0; mt < 4; mt++)
#pragma unroll
    for (int kc = 0; kc < 3; kc++)
      afc[mt][kc] = *(const short8*)(Kts + (mt * 16 + cl) * 104 + kc * 32 + quad * 8);

  unsigned short* dmb = DMu + ((int64_t)(c * 32 + b)) * 36864;
  union U8 { short8 s; uint32_t u[4]; };

  for (int mi = wv; mi < 9; mi += 4) {        // waves: {0,4,8},{1,5},{2,6},{3,7}
    uint32_t md[3][4];
#pragma unroll
    for (int kc = 0; kc < 3; kc++)
#pragma unroll
      for (int p = 0; p < 4; p++)
        md[kc][p] = ((sreg[kc][2 * p]     == (uint32_t)mi) ? 0x0000ffffu : 0u) |
                    ((sreg[kc][2 * p + 1] == (uint32_t)mi) ? 0xffff0000u : 0u);
#pragma unroll
    for (int nt = 0; nt < 4; nt++) {
      short8 bm[3];
#pragma unroll
      for (int kc = 0; kc < 3; kc++) {
        U8 vv; vv.s = *(const short8*)(Vts + (nt * 16 + cl) * 104 + kc * 32 + quad * 8);
        vv.u[0] &= md[kc][0]; vv.u[1] &= md[kc][1];
        vv.u[2] &= md[kc][2]; vv.u[3] &= md[kc][3];
        bm[kc] = vv.s;
      }
#pragma unroll
      for (int mt = 0; mt < 4; mt++) {
        floatx4 acc = (floatx4){0.f, 0.f, 0.f, 0.f};
#pragma unroll
        for (int kc = 0; kc < 3; kc++)
          acc = __builtin_amdgcn_mfma_f32_16x16x32_bf16(afc[mt][kc], bm[kc], acc, 0, 0, 0);
#pragma unroll
        for (int r = 0; r < 4; r++) {
          const int i = mt * 16 + quad * 4 + r, j = nt * 16 + cl;
          dmb[mi * 4096 + i * 64 + j] = (unsigned short)f2bf(acc[r]);
        }
      }
    }
  }
}

// ---------------- prefix: ΔM(bf16) -> Mstart(bf16) exclusive +M0; writes M_final fp32 ----------------
__global__ void prefix_kernel(const float* __restrict__ M0, uint32_t* __restrict__ DMh,
                              float* __restrict__ out, int nc)
{
  int64_t e = (int64_t)blockIdx.x * blockDim.x + threadIdx.x;   // < 32*18432 u32 units
  int b = (int)(e / DM_CB_U32);
  int r = (int)(e % DM_CB_U32);             // m*2048 + i*32 + jpair
  int m = r >> 11, rem = r & 2047, i = rem >> 5, jp = rem & 31;
  int64_t f32i = (int64_t)b * 36864 + m * 4096 + i * 64 + jp * 2;
  float run0 = M0[f32i], run1 = M0[f32i + 1];
  for (int cc = 0; cc < nc; cc++) {
    int64_t idx = ((int64_t)(cc * 32 + b)) * DM_CB_U32 + r;
    uint32_t u = DMh[idx];
    DMh[idx] = ((uint32_t)(unsigned short)f2bf(run0)) |
               (((uint32_t)(unsigned short)f2bf(run1)) << 16);
    run0 += bflo(u); run1 += bfhi(u);
  }
  *(float2*)(out + (int64_t)SEQ * BATCH * HID + f32i) = make_float2(run0, run1);
}

// ---------------- corr: o += q·(Mstart[0] + g0·Mstart[i0] + g1·Mstart[i1]) ----------------
// block = (b,c,jh). q read fp32 from Y; Mstart bf16 from DMh.
__global__ __launch_bounds__(256) void corr_kernel(
    const float* __restrict__ Y, const float4* __restrict__ gate,
    const uint32_t* __restrict__ DMh, float* __restrict__ out)
{
  __shared__ uint32_t Msb32[9 * 64 * 16];   // bf16 pairs [m][i][jpair-half] = 36.9KB
  __shared__ float2 qb[32 * 32];            // q fp32 pairs [t][i/2]
  __shared__ float4 gl[32];
  unsigned short* Msb = (unsigned short*)Msb32;
  const int blk = blockIdx.x;
  const int c   = blk & 7;
  const int jh  = (blk >> 3) & 1;
  const int b   = blk >> 4;
  const int tid = threadIdx.x;
  const int t0  = c * CHL;

  if (tid < 32) gl[tid] = gate[(t0 + tid) * BATCH + b];
#pragma unroll
  for (int k = 0; k < 4; k++) {
    int f = tid + 256 * k;                // < 1024
    int t = f >> 5, p = f & 31;
    qb[t * 32 + p] = *(const float2*)(Y + ((int64_t)(t0 + t) * BATCH + b) * NPAD + 1152 + 2 * p);
  }
  const uint32_t* dmb = DMh + ((int64_t)(c * 32 + b)) * DM_CB_U32;
#pragma unroll
  for (int k = 0; k < 36; k++) {
    int f = tid + 256 * k;                // < 9216 u32
    int m = f >> 10, rem = f & 1023, i = rem >> 4, p = rem & 15;
    Msb32[(m * 64 + i) * 16 + p] = dmb[m * 2048 + i * 32 + jh * 16 + p];
  }
  __syncthreads();

  const int jj = tid & 31;
  const int tg = tid >> 5;
#pragma unroll
  for (int tt = 0; tt < 4; tt++) {
    const int t = tt * 8 + tg;
    float4 g = gl[t];
    const int i0 = __float_as_int(g.x), i1 = __float_as_int(g.y);
    const float g0 = g.z, g1 = g.w;
    float acc = 0.f;
#pragma unroll 8
    for (int i2 = 0; i2 < 32; i2++) {
      float2 qq = qb[t * 32 + i2];
      int ia = 2 * i2;
      float m0a = bfu(Msb[(0  * 64 + ia) * 32 + jj]);
      float m0b = bfu(Msb[(0  * 64 + ia + 1) * 32 + jj]);
      float maa = bfu(Msb[(i0 * 64 + ia) * 32 + jj]);
      float mab = bfu(Msb[(i0 * 64 + ia + 1) * 32 + jj]);
      float mba = bfu(Msb[(i1 * 64 + ia) * 32 + jj]);
      float mbb = bfu(Msb[(i1 * 64 + ia + 1) * 32 + jj]);
      acc += qq.x * (m0a + g0 * maa + g1 * mba);
      acc += qq.y * (m0b + g0 * mab + g1 * mbb);
    }
    float* op = out + (int64_t)(t0 + t) * (BATCH * HID) + b * HID + jh * 32 + jj;
    *op += acc;
  }
}

// ---------------- launch ----------------
extern "C" void kernel_launch(void* const* d_in, const int* in_sizes, int n_in,
                              void* d_out, int out_size, void* d_ws, size_t ws_size,
                              hipStream_t stream)
{
  const float* X  = (const float*)d_in[0];
  const float* M0 = (const float*)d_in[1];
  const float* Wk = (const float*)d_in[2];
  const float* bk = (const float*)d_in[3];
  const float* Wv = (const float*)d_in[4];
  const float* bv = (const float*)d_in[5];
  const float* Wg = (const float*)d_in[6];
  const float* bg = (const float*)d_in[7];
  const float* Wq = (const float*)d_in[8];
  const float* bq = (const float*)d_in[9];

  char* ws = (char*)d_ws;
  short*          Xbf  = (short*)(ws + XBF_OFF);
  short*          Wbf  = (short*)(ws + WBF_OFF);
  float*          bb   = (float*)(ws + BB_OFF);
  float4*         gate = (float4*)(ws + GATE_OFF);
  float*          Y    = (float*)(ws + Y_OFF);
  uint32_t*       DMh  = (uint32_t*)(ws + DMH_OFF);        // overlays Xbf/Wbf (dead after gemm)
  unsigned short* DMu  = (unsigned short*)(ws + DMH_OFF);
  float*          out  = (float*)d_out;

  prep_gate_kernel<<<4096, 256, 0, stream>>>(X, Wk, bk, Wv, bv, Wg, bg, Wq, bq,
                                             Xbf, Wbf, bb, gate);
  dim3 gg(NPAD / 128, ROWS / 128);
  gemm_kernel<<<gg, 256, 0, stream>>>(Xbf, Wbf, bb, Y);
  mfma_chunk_kernel<<<32 * NC, 256, 0, stream>>>(Y, gate, DMu, out);
  prefix_kernel<<<(32 * DM_CB_U32) / 256, 256, 0, stream>>>(M0, DMh, out, NC);
  corr_kernel<<<32 * NC * 2, 256, 0, stream>>>(Y, gate, DMh, out);
}